// Round 1
// 547.163 us; speedup vs baseline: 1.0391x; 1.0391x over previous
//
#include <hip/hip_runtime.h>
#include <math.h>
#include <stdint.h>

#define NLEVELS 16
#define TSIZE   (1u << 19)
#define HMASK   (TSIZE - 1u)
#define P1 2654435761u
#define P2 805459861u

typedef float v2f __attribute__((ext_vector_type(2)));
typedef float v4f __attribute__((ext_vector_type(4)));

// Per-XCD secondary-stream schedule: up to 3 (level, count, base) segments
// covering the odd-j block slots. Even-j slots are always level 8+xcd.
struct LevelParams {
    float    cell[NLEVELS];
    uint32_t slvl[8][3];
    uint32_t scnt[8][3];
    uint32_t sbase[8][3];
};

__device__ __forceinline__ uint32_t bf16_rne(float f) {
    uint32_t b = __float_as_uint(f);
    return (b + 0x7FFFu + ((b >> 16) & 1u)) >> 16;   // round-to-nearest-even
}

// ---------------------------------------------------------------------------
// Phase 0: f32 tables -> packed bf16x2 (4 B/entry) in ws (rebuilt every call).
__global__ __launch_bounds__(256) void convert_tables_kernel(
    const v2f* __restrict__ tables, uint32_t* __restrict__ tab16,
    unsigned int nEntries)
{
    unsigned int i = blockIdx.x * 256u + threadIdx.x;
    if (i >= nEntries) return;
    v2f v = __builtin_nontemporal_load(&tables[i]);
    tab16[i] = (bf16_rne(v.x) << 16) | bf16_rne(v.y);
}

// ---------------------------------------------------------------------------
// Phase 1: compute, level-partitioned across XCDs (blockIdx%8 -> XCD).
// Even j: XCD k runs fine level 8+k (full 2 MiB table, ~all gathers miss L1
// and hit that XCD's L2). Odd j: a per-XCD "secondary" stream, scheduled so
// the per-XCD L2-MISS work is balanced (old pairing gave XCD6/7 two
// full-footprint tables each -> ~2x the L2-miss work of XCD0 -> whole kernel
// ran at the slowest XCD's pace):
//   XCD0..3: 1/4 of l7 (each caches whole l7 table; fp 4.0 MiB) + l0..l3
//   XCD4:    1/2 of l6 + tails of l0,l1          (fp ~3.1 MiB)
//   XCD5:    1/2 of l6 + tails of l2,l3          (fp ~3.1 MiB)
//   XCD6:    l5                                  (fp ~2.5 MiB)
//   XCD7:    l4                                  (fp ~2.3 MiB)
// Max per-XCD miss weight ~1.30 vs 2.0 before. Stage stores are nt
// (write-once, full-line coalesced); xyz uses cached loads (L3 absorbs the
// 16x re-read).
__global__ __launch_bounds__(256) void hashgrid_compute_kernel(
    const float* __restrict__ xyz,
    const uint32_t* __restrict__ tab16,
    v2f* __restrict__ stage,
    LevelParams lp,
    unsigned int npts)
{
    unsigned int b   = blockIdx.x;
    unsigned int xcd = b & 7u;
    unsigned int j   = b >> 3;

    unsigned int level, chunk;
    if (j & 1u) {
        unsigned int t = j >> 1;
        unsigned int s = 0;
        while (s < 2u && t >= lp.scnt[xcd][s]) { t -= lp.scnt[xcd][s]; ++s; }
        level = lp.slvl[xcd][s];
        chunk = lp.sbase[xcd][s] + t;
    } else {
        level = 8u + xcd;
        chunk = j >> 1;
    }
    unsigned int n = chunk * 256u + threadIdx.x;

    float x = xyz[n * 3 + 0];
    float y = xyz[n * 3 + 1];
    float z = xyz[n * 3 + 2];

    float cell = lp.cell[level];   // block-uniform

    // floor(x / cell) with IEEE-correct f32 division (matches reference)
    float fx = floorf(x / cell);
    float fy = floorf(y / cell);
    float fz = floorf(z / cell);

    float mvx = fx * cell, mvy = fy * cell, mvz = fz * cell;
    float dnx = (mvx + cell) - mvx;
    float dny = (mvy + cell) - mvy;
    float dnz = (mvz + cell) - mvz;

    float dx = (x - mvx) * __builtin_amdgcn_rcpf(dnx);
    float dy = (y - mvy) * __builtin_amdgcn_rcpf(dny);
    float dz = (z - mvz) * __builtin_amdgcn_rcpf(dnz);

    unsigned int ix = (unsigned int)(int)fx;
    unsigned int iy = (unsigned int)(int)fy;
    unsigned int iz = (unsigned int)(int)fz;

    unsigned int hx0 = ix,      hx1 = ix + 1u;
    unsigned int hy0 = iy * P1, hy1 = hy0 + P1;
    unsigned int hz0 = iz * P2, hz1 = hz0 + P2;

    const uint32_t* __restrict__ tab = tab16 + (size_t)level * TSIZE;

    uint32_t u0 = tab[(hx0 ^ hy0 ^ hz0) & HMASK];
    uint32_t u1 = tab[(hx0 ^ hy0 ^ hz1) & HMASK];
    uint32_t u2 = tab[(hx0 ^ hy1 ^ hz0) & HMASK];
    uint32_t u3 = tab[(hx0 ^ hy1 ^ hz1) & HMASK];
    uint32_t u4 = tab[(hx1 ^ hy0 ^ hz0) & HMASK];
    uint32_t u5 = tab[(hx1 ^ hy0 ^ hz1) & HMASK];
    uint32_t u6 = tab[(hx1 ^ hy1 ^ hz0) & HMASK];
    uint32_t u7 = tab[(hx1 ^ hy1 ^ hz1) & HMASK];

    #define UX(u) __uint_as_float((u) & 0xFFFF0000u)
    #define UY(u) __uint_as_float((u) << 16)

    float wx0 = 1.0f - dx, wy0 = 1.0f - dy, wz0 = 1.0f - dz;

    float c00x = UX(u0) * wx0 + UX(u4) * dx;
    float c00y = UY(u0) * wx0 + UY(u4) * dx;
    float c01x = UX(u1) * wx0 + UX(u5) * dx;
    float c01y = UY(u1) * wx0 + UY(u5) * dx;
    float c10x = UX(u2) * wx0 + UX(u6) * dx;
    float c10y = UY(u2) * wx0 + UY(u6) * dx;
    float c11x = UX(u3) * wx0 + UX(u7) * dx;
    float c11y = UY(u3) * wx0 + UY(u7) * dx;

    #undef UX
    #undef UY

    float c0x = c00x * wy0 + c10x * dy;
    float c0y = c00y * wy0 + c10y * dy;
    float c1x = c01x * wy0 + c11x * dy;
    float c1y = c01y * wy0 + c11y * dy;

    v2f r;
    r.x = c0x * wz0 + c1x * dz;
    r.y = c0y * wz0 + c1y * dz;

    __builtin_nontemporal_store(r, &stage[(size_t)level * npts + n]);
}

// ---------------------------------------------------------------------------
// Phase 2: transpose stage[l][n] -> out[n][l] via LDS.
// Loads: 16 coalesced level-major rows. LDS [256][17] float2 (pad 17 breaks
// the stride-16 bank pattern; write aliasing is 2-way = free). Stores: flat
// index blk*2048 + iter*256 + tid -> 1 KiB contiguous per wave instruction
// (16 full lines) so nt streaming stores are full-line and safe.
__global__ __launch_bounds__(256) void transpose_kernel(
    const v2f* __restrict__ stage, v4f* __restrict__ out4, unsigned int npts)
{
    __shared__ v2f lds[256][17];
    unsigned int tid  = threadIdx.x;
    unsigned int base = blockIdx.x * 256u;

#pragma unroll
    for (int l = 0; l < NLEVELS; ++l)
        lds[tid][l] = __builtin_nontemporal_load(&stage[(size_t)l * npts + base + tid]);

    __syncthreads();

#pragma unroll
    for (int it = 0; it < 8; ++it) {
        unsigned int i = it * 256u + tid;        // 0..2047 within block
        unsigned int p = i >> 3;                 // point within block
        unsigned int k = i & 7u;                 // float4 index within record
        v2f a = lds[p][2 * k];
        v2f c = lds[p][2 * k + 1];
        v4f w; w.x = a.x; w.y = a.y; w.z = c.x; w.w = c.y;
        __builtin_nontemporal_store(w, &out4[(size_t)blockIdx.x * 2048u + i]);
    }
}

// ---------------------------------------------------------------------------
// Fallback (round-1 kernel): direct f32 gathers, used only if ws is too small.
__global__ __launch_bounds__(256) void hashgrid_direct_kernel(
    const float* __restrict__ xyz,
    const float* __restrict__ tables,
    float2* __restrict__ out,
    LevelParams lp,
    unsigned int total)
{
    unsigned int t = blockIdx.x * 256u + threadIdx.x;
    if (t >= total) return;
    unsigned int n = t >> 4;
    unsigned int l = t & 15u;

    float x = xyz[n * 3 + 0], y = xyz[n * 3 + 1], z = xyz[n * 3 + 2];
    float cell = lp.cell[l];
    float fx = floorf(x / cell), fy = floorf(y / cell), fz = floorf(z / cell);
    float mvx = fx * cell, mvy = fy * cell, mvz = fz * cell;
    float dnx = (mvx + cell) - mvx, dny = (mvy + cell) - mvy, dnz = (mvz + cell) - mvz;
    float dx = (x - mvx) * __builtin_amdgcn_rcpf(dnx);
    float dy = (y - mvy) * __builtin_amdgcn_rcpf(dny);
    float dz = (z - mvz) * __builtin_amdgcn_rcpf(dnz);
    unsigned int ix = (unsigned int)(int)fx, iy = (unsigned int)(int)fy, iz = (unsigned int)(int)fz;
    unsigned int hx0 = ix, hx1 = ix + 1u;
    unsigned int hy0 = iy * P1, hy1 = hy0 + P1;
    unsigned int hz0 = iz * P2, hz1 = hz0 + P2;
    const float2* __restrict__ tab = (const float2*)tables + (size_t)l * TSIZE;
    float2 e0 = tab[(hx0 ^ hy0 ^ hz0) & HMASK];
    float2 e1 = tab[(hx0 ^ hy0 ^ hz1) & HMASK];
    float2 e2 = tab[(hx0 ^ hy1 ^ hz0) & HMASK];
    float2 e3 = tab[(hx0 ^ hy1 ^ hz1) & HMASK];
    float2 e4 = tab[(hx1 ^ hy0 ^ hz0) & HMASK];
    float2 e5 = tab[(hx1 ^ hy0 ^ hz1) & HMASK];
    float2 e6 = tab[(hx1 ^ hy1 ^ hz0) & HMASK];
    float2 e7 = tab[(hx1 ^ hy1 ^ hz1) & HMASK];
    float wx0 = 1.0f - dx, wy0 = 1.0f - dy, wz0 = 1.0f - dz;
    float c00x = e0.x * wx0 + e4.x * dx, c00y = e0.y * wx0 + e4.y * dx;
    float c01x = e1.x * wx0 + e5.x * dx, c01y = e1.y * wx0 + e5.y * dx;
    float c10x = e2.x * wx0 + e6.x * dx, c10y = e2.y * wx0 + e6.y * dx;
    float c11x = e3.x * wx0 + e7.x * dx, c11y = e3.y * wx0 + e7.y * dx;
    float c0x = c00x * wy0 + c10x * dy, c0y = c00y * wy0 + c10y * dy;
    float c1x = c01x * wy0 + c11x * dy, c1y = c01y * wy0 + c11y * dy;
    out[t] = make_float2(c0x * wz0 + c1x * dz, c0y * wz0 + c1y * dz);
}

// ---------------------------------------------------------------------------
extern "C" void kernel_launch(void* const* d_in, const int* in_sizes, int n_in,
                              void* d_out, int out_size, void* d_ws, size_t ws_size,
                              hipStream_t stream)
{
    const float* xyz    = (const float*)d_in[0];
    const float* tables = (const float*)d_in[1];

    // Resolutions via the SAME libm calls CPython makes (bit-exact floors).
    LevelParams lp;
    double bg = exp((log(512.0) - log(16.0)) / 15.0);
    for (int i = 0; i < NLEVELS; ++i) {
        int res = (int)floor(16.0 * pow(bg, (double)i));
        lp.cell[i] = 1.0f / (float)res;
    }

    unsigned int npts = (unsigned int)(in_sizes[0] / 3);
    size_t tabBytes   = (size_t)NLEVELS * TSIZE * 4u;         // 32 MiB
    size_t stageBytes = (size_t)npts * NLEVELS * sizeof(v2f); // 128 MiB

    if (ws_size >= tabBytes + stageBytes && (npts & 255u) == 0u) {
        uint32_t* tab16 = (uint32_t*)d_ws;
        v2f* stage = (v2f*)((char*)d_ws + tabBytes);

        unsigned int nEntries = NLEVELS * TSIZE;
        hipLaunchKernelGGL(convert_tables_kernel,
                           dim3((nEntries + 255u) / 256u), dim3(256), 0, stream,
                           (const v2f*)tables, tab16, nEntries);

        unsigned int chunks = npts / 256u;                  // 4096 for N_PTS=2^20

        // Build the secondary (odd-j) schedule, balancing per-XCD L2-miss work.
        for (int x = 0; x < 8; ++x)
            for (int s = 0; s < 3; ++s) {
                lp.slvl[x][s] = 0; lp.scnt[x][s] = 0; lp.sbase[x][s] = 0;
            }
        if ((chunks & 3u) == 0u) {
            unsigned int q = chunks / 4u;
            // XCD0..3: quarter of l7 + one tiny level (3/4 of it)
            for (int x = 0; x < 4; ++x) {
                lp.slvl[x][0] = 7;         lp.scnt[x][0] = q;      lp.sbase[x][0] = (unsigned)x * q;
                lp.slvl[x][1] = (unsigned)x; lp.scnt[x][1] = 3u * q; lp.sbase[x][1] = 0;
            }
            // XCD4: half of l6 + tails of l0,l1
            lp.slvl[4][0] = 6; lp.scnt[4][0] = 2u * q; lp.sbase[4][0] = 0;
            lp.slvl[4][1] = 0; lp.scnt[4][1] = q;      lp.sbase[4][1] = 3u * q;
            lp.slvl[4][2] = 1; lp.scnt[4][2] = q;      lp.sbase[4][2] = 3u * q;
            // XCD5: half of l6 + tails of l2,l3
            lp.slvl[5][0] = 6; lp.scnt[5][0] = 2u * q; lp.sbase[5][0] = 2u * q;
            lp.slvl[5][1] = 2; lp.scnt[5][1] = q;      lp.sbase[5][1] = 3u * q;
            lp.slvl[5][2] = 3; lp.scnt[5][2] = q;      lp.sbase[5][2] = 3u * q;
            // XCD6: all of l5.  XCD7: all of l4.
            lp.slvl[6][0] = 5; lp.scnt[6][0] = chunks; lp.sbase[6][0] = 0;
            lp.slvl[7][0] = 4; lp.scnt[7][0] = chunks; lp.sbase[7][0] = 0;
        } else {
            // Generic fallback schedule: old pairing (xcd -> coarse level xcd)
            for (int x = 0; x < 8; ++x) {
                lp.slvl[x][0] = (unsigned)x; lp.scnt[x][0] = chunks; lp.sbase[x][0] = 0;
            }
        }

        hipLaunchKernelGGL(hashgrid_compute_kernel,
                           dim3(NLEVELS * chunks), dim3(256), 0, stream,
                           xyz, tab16, stage, lp, npts);

        hipLaunchKernelGGL(transpose_kernel,
                           dim3(chunks), dim3(256), 0, stream,
                           stage, (v4f*)d_out, npts);
    } else {
        unsigned int total = npts * (unsigned int)NLEVELS;
        hipLaunchKernelGGL(hashgrid_direct_kernel,
                           dim3((total + 255u) / 256u), dim3(256), 0, stream,
                           xyz, tables, (float2*)d_out, lp, total);
    }
}

// Round 2
// 546.010 us; speedup vs baseline: 1.0413x; 1.0021x over previous
//
#include <hip/hip_runtime.h>
#include <math.h>
#include <stdint.h>

#define NLEVELS 16
#define TSIZE   (1u << 19)
#define HMASK   (TSIZE - 1u)
#define P1 2654435761u
#define P2 805459861u

typedef float v2f __attribute__((ext_vector_type(2)));
typedef float v4f __attribute__((ext_vector_type(4)));
typedef uint32_t u32x4 __attribute__((ext_vector_type(4)));

// Per-XCD secondary-stream schedule: up to 3 (level, count, base) segments
// covering the odd-j block slots. Even-j slots are always level 8+xcd.
struct LevelParams {
    float    cell[NLEVELS];
    uint32_t slvl[8][3];
    uint32_t scnt[8][3];
    uint32_t sbase[8][3];
};

__device__ __forceinline__ uint32_t bf16_rne(float f) {
    uint32_t b = __float_as_uint(f);
    return (b + 0x7FFFu + ((b >> 16) & 1u)) >> 16;   // round-to-nearest-even
}

// Dynamic 4-way select via cndmask chain (NOT a runtime vector index -> no
// scratch; see rule #20).
__device__ __forceinline__ uint32_t sel4(u32x4 q, unsigned int s) {
    uint32_t lo = (s & 1u) ? q.y : q.x;
    uint32_t hi = (s & 1u) ? q.w : q.z;
    return (s & 2u) ? hi : lo;
}

// ---------------------------------------------------------------------------
// Phase 0: f32 tables -> packed bf16x2 (4 B/entry) in ws (rebuilt every call).
__global__ __launch_bounds__(256) void convert_tables_kernel(
    const v2f* __restrict__ tables, uint32_t* __restrict__ tab16,
    unsigned int nEntries)
{
    unsigned int i = blockIdx.x * 256u + threadIdx.x;
    if (i >= nEntries) return;
    v2f v = __builtin_nontemporal_load(&tables[i]);
    tab16[i] = (bf16_rne(v.x) << 16) | bf16_rne(v.y);
}

// ---------------------------------------------------------------------------
// Phase 1: compute, level-partitioned across XCDs (blockIdx%8 -> XCD).
// Even j: XCD k runs fine level 8+k. Odd j: per-XCD secondary stream,
// scheduled so per-XCD L2-miss work is balanced (round-1 win).
//
// Gather-pair merge (round-2): the x-prime is 1, so the two x-corners of any
// pair hash to b and b^off with off = ix^(ix+1). For off<=3 (75% of lanes)
// both entries are inside one aligned 16B quad -> one dwordx4 gather per
// pair (4 instead of 8 scattered requests). Only off>=7 lanes (25%) issue
// the 4 partner gathers, exec-masked. Per-wave scattered requests:
// 512 -> ~320 (-37.5%). Extracted values are bit-identical.
__global__ __launch_bounds__(256) void hashgrid_compute_kernel(
    const float* __restrict__ xyz,
    const uint32_t* __restrict__ tab16,
    v2f* __restrict__ stage,
    LevelParams lp,
    unsigned int npts)
{
    unsigned int b   = blockIdx.x;
    unsigned int xcd = b & 7u;
    unsigned int j   = b >> 3;

    unsigned int level, chunk;
    if (j & 1u) {
        unsigned int t = j >> 1;
        unsigned int s = 0;
        while (s < 2u && t >= lp.scnt[xcd][s]) { t -= lp.scnt[xcd][s]; ++s; }
        level = lp.slvl[xcd][s];
        chunk = lp.sbase[xcd][s] + t;
    } else {
        level = 8u + xcd;
        chunk = j >> 1;
    }
    unsigned int n = chunk * 256u + threadIdx.x;

    float x = xyz[n * 3 + 0];
    float y = xyz[n * 3 + 1];
    float z = xyz[n * 3 + 2];

    float cell = lp.cell[level];   // block-uniform

    // floor(x / cell) with IEEE-correct f32 division (matches reference)
    float fx = floorf(x / cell);
    float fy = floorf(y / cell);
    float fz = floorf(z / cell);

    float mvx = fx * cell, mvy = fy * cell, mvz = fz * cell;
    float dnx = (mvx + cell) - mvx;
    float dny = (mvy + cell) - mvy;
    float dnz = (mvz + cell) - mvz;

    float dx = (x - mvx) * __builtin_amdgcn_rcpf(dnx);
    float dy = (y - mvy) * __builtin_amdgcn_rcpf(dny);
    float dz = (z - mvz) * __builtin_amdgcn_rcpf(dnz);

    unsigned int ix = (unsigned int)(int)fx;
    unsigned int iy = (unsigned int)(int)fy;
    unsigned int iz = (unsigned int)(int)fz;

    unsigned int hy0 = iy * P1, hy1 = hy0 + P1;
    unsigned int hz0 = iz * P2, hz1 = hz0 + P2;

    unsigned int b0 = (ix ^ hy0 ^ hz0) & HMASK;
    unsigned int b1 = (ix ^ hy0 ^ hz1) & HMASK;
    unsigned int b2 = (ix ^ hy1 ^ hz0) & HMASK;
    unsigned int b3 = (ix ^ hy1 ^ hz1) & HMASK;
    unsigned int off = ix ^ (ix + 1u);   // 1,3,7,15,... ; partner = b ^ off

    const uint32_t* __restrict__ tab = tab16 + (size_t)level * TSIZE;
    const u32x4*   __restrict__ tb4 = (const u32x4*)tab;

    // 4 quad gathers cover all low corners (and the partners when off<=3).
    u32x4 q0 = tb4[b0 >> 2];
    u32x4 q1 = tb4[b1 >> 2];
    u32x4 q2 = tb4[b2 >> 2];
    u32x4 q3 = tb4[b3 >> 2];

    unsigned int s0 = b0 & 3u, s1 = b1 & 3u, s2 = b2 & 3u, s3 = b3 & 3u;
    uint32_t u0 = sel4(q0, s0);
    uint32_t u1 = sel4(q1, s1);
    uint32_t u2 = sel4(q2, s2);
    uint32_t u3 = sel4(q3, s3);

    uint32_t u4, u5, u6, u7;
    if (off <= 3u) {                      // 75% of lanes: partner in the quad
        u4 = sel4(q0, s0 ^ off);
        u5 = sel4(q1, s1 ^ off);
        u6 = sel4(q2, s2 ^ off);
        u7 = sel4(q3, s3 ^ off);
    } else {                              // 25% of lanes: 4 masked gathers
        u4 = tab[(b0 ^ off) & HMASK];
        u5 = tab[(b1 ^ off) & HMASK];
        u6 = tab[(b2 ^ off) & HMASK];
        u7 = tab[(b3 ^ off) & HMASK];
    }

    #define UX(u) __uint_as_float((u) & 0xFFFF0000u)
    #define UY(u) __uint_as_float((u) << 16)

    float wx0 = 1.0f - dx, wy0 = 1.0f - dy, wz0 = 1.0f - dz;

    float c00x = UX(u0) * wx0 + UX(u4) * dx;
    float c00y = UY(u0) * wx0 + UY(u4) * dx;
    float c01x = UX(u1) * wx0 + UX(u5) * dx;
    float c01y = UY(u1) * wx0 + UY(u5) * dx;
    float c10x = UX(u2) * wx0 + UX(u6) * dx;
    float c10y = UY(u2) * wx0 + UY(u6) * dx;
    float c11x = UX(u3) * wx0 + UX(u7) * dx;
    float c11y = UY(u3) * wx0 + UY(u7) * dx;

    #undef UX
    #undef UY

    float c0x = c00x * wy0 + c10x * dy;
    float c0y = c00y * wy0 + c10y * dy;
    float c1x = c01x * wy0 + c11x * dy;
    float c1y = c01y * wy0 + c11y * dy;

    v2f r;
    r.x = c0x * wz0 + c1x * dz;
    r.y = c0y * wz0 + c1y * dz;

    __builtin_nontemporal_store(r, &stage[(size_t)level * npts + n]);
}

// ---------------------------------------------------------------------------
// Phase 2: transpose stage[l][n] -> out[n][l] via LDS.
// Loads: 16 coalesced level-major rows. LDS [256][17] float2 (pad 17 breaks
// the stride-16 bank pattern; write aliasing is 2-way = free). Stores: flat
// index blk*2048 + iter*256 + tid -> 1 KiB contiguous per wave instruction
// (16 full lines) so nt streaming stores are full-line and safe.
__global__ __launch_bounds__(256) void transpose_kernel(
    const v2f* __restrict__ stage, v4f* __restrict__ out4, unsigned int npts)
{
    __shared__ v2f lds[256][17];
    unsigned int tid  = threadIdx.x;
    unsigned int base = blockIdx.x * 256u;

#pragma unroll
    for (int l = 0; l < NLEVELS; ++l)
        lds[tid][l] = __builtin_nontemporal_load(&stage[(size_t)l * npts + base + tid]);

    __syncthreads();

#pragma unroll
    for (int it = 0; it < 8; ++it) {
        unsigned int i = it * 256u + tid;        // 0..2047 within block
        unsigned int p = i >> 3;                 // point within block
        unsigned int k = i & 7u;                 // float4 index within record
        v2f a = lds[p][2 * k];
        v2f c = lds[p][2 * k + 1];
        v4f w; w.x = a.x; w.y = a.y; w.z = c.x; w.w = c.y;
        __builtin_nontemporal_store(w, &out4[(size_t)blockIdx.x * 2048u + i]);
    }
}

// ---------------------------------------------------------------------------
// Fallback (round-1 kernel): direct f32 gathers, used only if ws is too small.
__global__ __launch_bounds__(256) void hashgrid_direct_kernel(
    const float* __restrict__ xyz,
    const float* __restrict__ tables,
    float2* __restrict__ out,
    LevelParams lp,
    unsigned int total)
{
    unsigned int t = blockIdx.x * 256u + threadIdx.x;
    if (t >= total) return;
    unsigned int n = t >> 4;
    unsigned int l = t & 15u;

    float x = xyz[n * 3 + 0], y = xyz[n * 3 + 1], z = xyz[n * 3 + 2];
    float cell = lp.cell[l];
    float fx = floorf(x / cell), fy = floorf(y / cell), fz = floorf(z / cell);
    float mvx = fx * cell, mvy = fy * cell, mvz = fz * cell;
    float dnx = (mvx + cell) - mvx, dny = (mvy + cell) - mvy, dnz = (mvz + cell) - mvz;
    float dx = (x - mvx) * __builtin_amdgcn_rcpf(dnx);
    float dy = (y - mvy) * __builtin_amdgcn_rcpf(dny);
    float dz = (z - mvz) * __builtin_amdgcn_rcpf(dnz);
    unsigned int ix = (unsigned int)(int)fx, iy = (unsigned int)(int)fy, iz = (unsigned int)(int)fz;
    unsigned int hx0 = ix, hx1 = ix + 1u;
    unsigned int hy0 = iy * P1, hy1 = hy0 + P1;
    unsigned int hz0 = iz * P2, hz1 = hz0 + P2;
    const float2* __restrict__ tab = (const float2*)tables + (size_t)l * TSIZE;
    float2 e0 = tab[(hx0 ^ hy0 ^ hz0) & HMASK];
    float2 e1 = tab[(hx0 ^ hy0 ^ hz1) & HMASK];
    float2 e2 = tab[(hx0 ^ hy1 ^ hz0) & HMASK];
    float2 e3 = tab[(hx0 ^ hy1 ^ hz1) & HMASK];
    float2 e4 = tab[(hx1 ^ hy0 ^ hz0) & HMASK];
    float2 e5 = tab[(hx1 ^ hy0 ^ hz1) & HMASK];
    float2 e6 = tab[(hx1 ^ hy1 ^ hz0) & HMASK];
    float2 e7 = tab[(hx1 ^ hy1 ^ hz1) & HMASK];
    float wx0 = 1.0f - dx, wy0 = 1.0f - dy, wz0 = 1.0f - dz;
    float c00x = e0.x * wx0 + e4.x * dx, c00y = e0.y * wx0 + e4.y * dx;
    float c01x = e1.x * wx0 + e5.x * dx, c01y = e1.y * wx0 + e5.y * dx;
    float c10x = e2.x * wx0 + e6.x * dx, c10y = e2.y * wx0 + e6.y * dx;
    float c11x = e3.x * wx0 + e7.x * dx, c11y = e3.y * wx0 + e7.y * dx;
    float c0x = c00x * wy0 + c10x * dy, c0y = c00y * wy0 + c10y * dy;
    float c1x = c01x * wy0 + c11x * dy, c1y = c01y * wy0 + c11y * dy;
    out[t] = make_float2(c0x * wz0 + c1x * dz, c0y * wz0 + c1y * dz);
}

// ---------------------------------------------------------------------------
extern "C" void kernel_launch(void* const* d_in, const int* in_sizes, int n_in,
                              void* d_out, int out_size, void* d_ws, size_t ws_size,
                              hipStream_t stream)
{
    const float* xyz    = (const float*)d_in[0];
    const float* tables = (const float*)d_in[1];

    // Resolutions via the SAME libm calls CPython makes (bit-exact floors).
    LevelParams lp;
    double bg = exp((log(512.0) - log(16.0)) / 15.0);
    for (int i = 0; i < NLEVELS; ++i) {
        int res = (int)floor(16.0 * pow(bg, (double)i));
        lp.cell[i] = 1.0f / (float)res;
    }

    unsigned int npts = (unsigned int)(in_sizes[0] / 3);
    size_t tabBytes   = (size_t)NLEVELS * TSIZE * 4u;         // 32 MiB
    size_t stageBytes = (size_t)npts * NLEVELS * sizeof(v2f); // 128 MiB

    if (ws_size >= tabBytes + stageBytes && (npts & 255u) == 0u) {
        uint32_t* tab16 = (uint32_t*)d_ws;
        v2f* stage = (v2f*)((char*)d_ws + tabBytes);

        unsigned int nEntries = NLEVELS * TSIZE;
        hipLaunchKernelGGL(convert_tables_kernel,
                           dim3((nEntries + 255u) / 256u), dim3(256), 0, stream,
                           (const v2f*)tables, tab16, nEntries);

        unsigned int chunks = npts / 256u;                  // 4096 for N_PTS=2^20

        // Build the secondary (odd-j) schedule, balancing per-XCD L2-miss work.
        for (int x = 0; x < 8; ++x)
            for (int s = 0; s < 3; ++s) {
                lp.slvl[x][s] = 0; lp.scnt[x][s] = 0; lp.sbase[x][s] = 0;
            }
        if ((chunks & 3u) == 0u) {
            unsigned int q = chunks / 4u;
            // XCD0..3: quarter of l7 + one tiny level (3/4 of it)
            for (int x = 0; x < 4; ++x) {
                lp.slvl[x][0] = 7;         lp.scnt[x][0] = q;      lp.sbase[x][0] = (unsigned)x * q;
                lp.slvl[x][1] = (unsigned)x; lp.scnt[x][1] = 3u * q; lp.sbase[x][1] = 0;
            }
            // XCD4: half of l6 + tails of l0,l1
            lp.slvl[4][0] = 6; lp.scnt[4][0] = 2u * q; lp.sbase[4][0] = 0;
            lp.slvl[4][1] = 0; lp.scnt[4][1] = q;      lp.sbase[4][1] = 3u * q;
            lp.slvl[4][2] = 1; lp.scnt[4][2] = q;      lp.sbase[4][2] = 3u * q;
            // XCD5: half of l6 + tails of l2,l3
            lp.slvl[5][0] = 6; lp.scnt[5][0] = 2u * q; lp.sbase[5][0] = 2u * q;
            lp.slvl[5][1] = 2; lp.scnt[5][1] = q;      lp.sbase[5][1] = 3u * q;
            lp.slvl[5][2] = 3; lp.scnt[5][2] = q;      lp.sbase[5][2] = 3u * q;
            // XCD6: all of l5.  XCD7: all of l4.
            lp.slvl[6][0] = 5; lp.scnt[6][0] = chunks; lp.sbase[6][0] = 0;
            lp.slvl[7][0] = 4; lp.scnt[7][0] = chunks; lp.sbase[7][0] = 0;
        } else {
            // Generic fallback schedule: old pairing (xcd -> coarse level xcd)
            for (int x = 0; x < 8; ++x) {
                lp.slvl[x][0] = (unsigned)x; lp.scnt[x][0] = chunks; lp.sbase[x][0] = 0;
            }
        }

        hipLaunchKernelGGL(hashgrid_compute_kernel,
                           dim3(NLEVELS * chunks), dim3(256), 0, stream,
                           xyz, tab16, stage, lp, npts);

        hipLaunchKernelGGL(transpose_kernel,
                           dim3(chunks), dim3(256), 0, stream,
                           stage, (v4f*)d_out, npts);
    } else {
        unsigned int total = npts * (unsigned int)NLEVELS;
        hipLaunchKernelGGL(hashgrid_direct_kernel,
                           dim3((total + 255u) / 256u), dim3(256), 0, stream,
                           xyz, tables, (float2*)d_out, lp, total);
    }
}